// Round 4
// baseline (272.962 us; speedup 1.0000x reference)
//
#include <hip/hip_runtime.h>
#include <hip/hip_cooperative_groups.h>

namespace cg = cooperative_groups;

#define S_TOK 8192
#define NB 8
#define HQ 32
#define HKV 8
#define DH 128
#define KK 128
#define DIM 4096
#define NCOL4 (DIM / 4)   // 1024

// ---------------- GEMV: 2 rows per wave, x register-shared across rows ----------------
// Wave wv handles row pairs p = wv, wv+8, ... ; lane covers columns lane + it*64.
// x (128 KB) is read from L2 once per wave (shared across the 2 rows in registers),
// W rows stream from HBM fully coalesced (64 lanes x 16 B).
__device__ __forceinline__ void gemv_rows(const float* __restrict__ W,
                                          const float* __restrict__ x,
                                          float* __restrict__ y,
                                          int rstart, int rcnt, int t) {
    const int wv = t >> 6, lane = t & 63;
    const float4* W4 = (const float4*)W;
    const float4* x4 = (const float4*)x;
    for (int p = wv; 2 * p < rcnt; p += 8) {
        const int r0 = rstart + 2 * p;
        const bool has1 = (2 * p + 1) < rcnt;
        const int r1 = has1 ? (r0 + 1) : r0;
        float acc0[NB], acc1[NB];
#pragma unroll
        for (int b = 0; b < NB; ++b) { acc0[b] = 0.f; acc1[b] = 0.f; }
#pragma unroll 2
        for (int it = 0; it < 16; ++it) {
            const int c = lane + it * 64;
            float4 w0 = W4[(size_t)r0 * NCOL4 + c];
            float4 w1 = W4[(size_t)r1 * NCOL4 + c];
#pragma unroll
            for (int b = 0; b < NB; ++b) {
                float4 xv = x4[(size_t)b * NCOL4 + c];
                acc0[b] += w0.x * xv.x + w0.y * xv.y + w0.z * xv.z + w0.w * xv.w;
                acc1[b] += w1.x * xv.x + w1.y * xv.y + w1.z * xv.z + w1.w * xv.w;
            }
        }
#pragma unroll
        for (int b = 0; b < NB; ++b) {
#pragma unroll
            for (int o = 32; o > 0; o >>= 1) {
                acc0[b] += __shfl_down(acc0[b], o);
                acc1[b] += __shfl_down(acc1[b], o);
            }
        }
        if (lane == 0) {
#pragma unroll
            for (int b = 0; b < NB; ++b) {
                y[(size_t)b * DIM + r0] = acc0[b];
                if (has1) y[(size_t)b * DIM + r1] = acc1[b];
            }
        }
    }
}

__global__ __launch_bounds__(512, 1) void mega_kernel(
    const float* __restrict__ hidden, const float* __restrict__ attn_w,
    const float* __restrict__ kbuf, const float* __restrict__ vbuf,
    const float* __restrict__ Wq, const float* __restrict__ Wo,
    float* __restrict__ out, float* __restrict__ probs,
    unsigned* __restrict__ impbits, int* __restrict__ topkbuf,
    float* __restrict__ q, float* __restrict__ ctx) {

    __shared__ __align__(16) unsigned mb[S_TOK];   // 32 KB (topk)
    __shared__ __align__(16) int hist[256];
    __shared__ unsigned sprefix;
    __shared__ int skrem;
    __shared__ int nsel;
    __shared__ unsigned selb[KK];
    __shared__ int seli[KK];
    __shared__ float qs[DH];
    __shared__ float scs[KK];
    __shared__ float ps[KK];
    __shared__ int idxs[KK];
    __shared__ float red2[2];
    __shared__ float red3[2];
    __shared__ float part[3][DH];

    cg::grid_group grid = cg::this_grid();
    const int t = threadIdx.x;
    const int bl = blockIdx.x;

    // ========== Phase A: importance, serial h=0..31 sum (bit-exact vs verified R3) ====
    // 16384 float4-units spread as 64 units per block (wave 0). Fully parallel 8.4 MB read.
    if (t < 64) {
        const int u = bl * 64 + t;          // 256*64 = 16384 = NB*S_TOK/4
        const int b = u >> 11;              // 2048 units per batch
        const int base = (u & 2047) * 4;
        float4 acc = {0.f, 0.f, 0.f, 0.f};
#pragma unroll 8
        for (int h = 0; h < HQ; ++h) {
            float4 w = *(const float4*)(attn_w + (size_t)(b * HQ + h) * S_TOK + base);
            acc.x += w.x; acc.y += w.y; acc.z += w.z; acc.w += w.w;
        }
        float vals[4] = {acc.x, acc.y, acc.z, acc.w};
#pragma unroll
        for (int j = 0; j < 4; ++j) {
            unsigned uu = __float_as_uint(vals[j] * (1.0f / 32.0f));
            uu = (uu & 0x80000000u) ? ~uu : (uu | 0x80000000u);   // monotone map
            impbits[(size_t)b * S_TOK + base + j] = uu;
        }
    }
    __threadfence();
    grid.sync();

    // ========== Phase B: topk (blocks 0..7) + Wq GEMV (all blocks) ====================
    if (bl < NB) {
        const int b = bl;
        const unsigned* ip = impbits + (size_t)b * S_TOK;
        for (int i = t; i < S_TOK; i += 512) mb[i] = ip[i];
        if (t == 0) { sprefix = 0u; skrem = KK; nsel = 0; }
        __syncthreads();

        // radix-256 select: bit pattern T of the 128th largest
        for (int shift = 24; shift >= 0; shift -= 8) {
            if (t < 256) hist[t] = 0;
            __syncthreads();
            const unsigned pfx = sprefix;
            const int krem = skrem;
            if (shift == 24) {
                // values cluster into few exponent bins -> ballot-aggregate
                for (int i = t; i < S_TOK; i += 512) {
                    int bin = mb[i] >> 24;
                    unsigned long long rem = __ballot(1);
                    while (rem) {
                        int fl = (int)__builtin_ctzll(rem);
                        int fbin = __shfl(bin, fl);
                        unsigned long long match = __ballot(bin == fbin);
                        if ((t & 63) == fl) atomicAdd(&hist[fbin], (int)__popcll(match));
                        rem &= ~match;
                    }
                }
            } else {
                const unsigned pmask = 0xFFFFFFFFu << (shift + 8);
                for (int i = t; i < S_TOK; i += 512) {
                    unsigned u = mb[i];
                    if ((u & pmask) == pfx) atomicAdd(&hist[(u >> shift) & 255], 1);
                }
            }
            __syncthreads();
            // wave 0: parallel descending-bin scan
            if (t < 64) {
                int4 h4 = *(const int4*)&hist[252 - 4 * t];
                int h0 = h4.w, h1 = h4.z, h2 = h4.y, h3 = h4.x;   // descending-bin order
                int c0 = h0, c1 = c0 + h1, c2 = c1 + h2, c3 = c2 + h3;
                int inc = c3;
#pragma unroll
                for (int o = 1; o < 64; o <<= 1) {
                    int yv = __shfl_up(inc, o);
                    if (t >= o) inc += yv;
                }
                int excl = inc - c3;
                int cand = -1, before = 0;
                if      (excl + c0 >= krem) { cand = 0; before = excl; }
                else if (excl + c1 >= krem) { cand = 1; before = excl + c0; }
                else if (excl + c2 >= krem) { cand = 2; before = excl + c1; }
                else if (excl + c3 >= krem) { cand = 3; before = excl + c2; }
                unsigned long long ball = __ballot(cand >= 0);
                int win = (int)__builtin_ctzll(ball);
                if (t == win) {
                    int p = 4 * t + cand;
                    sprefix = pfx | ((unsigned)(255 - p) << shift);
                    skrem = krem - before;
                }
            }
            __syncthreads();
        }
        const unsigned T = sprefix;

        // collect strictly-greater (unordered; sorted below)
        for (int i = t; i < S_TOK; i += 512) {
            unsigned u = mb[i];
            if (u > T) {
                int p = atomicAdd(&nsel, 1);
                selb[p] = u; seli[p] = i;
            }
        }
        __syncthreads();
        const int g = nsel;
        const int r = KK - g;          // >= 1 by construction

        // wave 0: ordered scan collects the r smallest-index ties
        if (t < 64) {
            int found = 0;
            for (int base0 = 0; base0 < S_TOK && found < r; base0 += 64) {
                bool is_tie = (mb[base0 + t] == T);
                unsigned long long ball = __ballot(is_tie);
                int pos = (int)__popcll(ball & ((1ull << t) - 1ull));
                if (is_tie && found + pos < r) {
                    selb[g + found + pos] = T;
                    seli[g + found + pos] = base0 + t;
                }
                found += (int)__popcll(ball);
            }
        }
        __syncthreads();

        // bitonic sort 128: value descending, index ascending
        for (int ksz = 2; ksz <= KK; ksz <<= 1) {
            for (int j = ksz >> 1; j > 0; j >>= 1) {
                if (t < KK) {
                    int i = t, l = i ^ j;
                    if (l > i) {
                        bool up = ((i & ksz) == 0);
                        unsigned ab = selb[i], cb = selb[l];
                        int ai = seli[i], ci = seli[l];
                        bool aFirst = (ab > cb) || (ab == cb && ai < ci);
                        if (up ? !aFirst : aFirst) {
                            selb[i] = cb; selb[l] = ab;
                            seli[i] = ci; seli[l] = ai;
                        }
                    }
                }
                __syncthreads();
            }
        }
        if (t < KK) topkbuf[b * KK + t] = seli[t];
    }

    // Wq GEMV: blocks 0-7 get 6 rows (after topk); of the rest, first 80 get 17,
    // remaining 168 get 16  (48 + 80*17 + 168*16 = 4096).
    {
        int rstart, rcnt;
        if (bl < NB) { rstart = bl * 6; rcnt = 6; }
        else {
            int idx = bl - NB;
            int extra = (idx < 80) ? idx : 80;
            rstart = 48 + idx * 16 + extra;
            rcnt = 16 + ((idx < 80) ? 1 : 0);
        }
        gemv_rows(Wq, hidden, q, rstart, rcnt, t);
    }
    __threadfence();
    grid.sync();

    // ========== Phase C: pruned attention, one block per (b,h) =======================
    {
        const int b = bl >> 5, h = bl & 31, kvh = h >> 2;

        if (t < DH) qs[t] = q[(size_t)(b * HQ + h) * DH + t] * 0.088388347648318447f;
        if (t < KK) idxs[t] = topkbuf[b * KK + t];
        __syncthreads();

        // scores: 4 threads per token, 32-dim quarter dots
        {
            const int tok = t >> 2, qpart = t & 3;
            const float4* k4 = (const float4*)(kbuf +
                ((size_t)(b * HKV + kvh) * S_TOK + idxs[tok]) * DH + qpart * 32);
            float sc = 0.f;
#pragma unroll
            for (int d4 = 0; d4 < 8; ++d4) {
                float4 kv = k4[d4];
                int d0 = qpart * 32 + d4 * 4;
                sc += qs[d0] * kv.x + qs[d0 + 1] * kv.y + qs[d0 + 2] * kv.z + qs[d0 + 3] * kv.w;
            }
            sc += __shfl_xor(sc, 1);
            sc += __shfl_xor(sc, 2);
            if (qpart == 0) scs[tok] = sc;
        }
        __syncthreads();

        // softmax over 128 tokens (threads 0..127 hold one token each)
        float sc = (t < KK) ? scs[t] : -3.4e38f;
        if (t < KK) {
            float m = sc;
            for (int o = 32; o > 0; o >>= 1) m = fmaxf(m, __shfl_down(m, o));
            if ((t & 63) == 0) red2[t >> 6] = m;
        }
        __syncthreads();
        const float mx = fmaxf(red2[0], red2[1]);
        float p = 0.f;
        if (t < KK) {
            p = expf(sc - mx);
            float sm = p;
            for (int o = 32; o > 0; o >>= 1) sm += __shfl_down(sm, o);
            if ((t & 63) == 0) red3[t >> 6] = sm;
        }
        __syncthreads();
        if (t < KK) {
            p /= (red3[0] + red3[1]);
            ps[t] = p;
            probs[(size_t)(b * HQ + h) * KK + t] = p;
        }
        __syncthreads();

        // PV: 4 groups x 128 dims, 32 tokens per group, LDS combine
        {
            const int d = t & (DH - 1), grp = t >> 7;
            const float* vbase = vbuf + (size_t)(b * HKV + kvh) * S_TOK * DH;
            float acc = 0.f;
            const int s0 = grp * 32;
#pragma unroll 4
            for (int s2 = s0; s2 < s0 + 32; ++s2) {
                acc += ps[s2] * vbase[(size_t)idxs[s2] * DH + d];
            }
            if (grp) part[grp - 1][d] = acc;
            __syncthreads();
            if (grp == 0)
                ctx[(size_t)(b * HQ + h) * DH + d] = acc + part[0][d] + part[1][d] + part[2][d];
        }
    }
    __threadfence();
    grid.sync();

    // ========== Phase D: Wo GEMV, exactly 16 rows per block ==========================
    gemv_rows(Wo, ctx, out, bl * 16, 16, t);
}

// ---------------- launcher ----------------
extern "C" void kernel_launch(void* const* d_in, const int* in_sizes, int n_in,
                              void* d_out, int out_size, void* d_ws, size_t ws_size,
                              hipStream_t stream) {
    const float* hidden = (const float*)d_in[0];   // [8,1,4096]
    const float* attn_w = (const float*)d_in[1];   // [8,32,1,8192]
    const float* kbuf   = (const float*)d_in[2];   // [8,8,8192,128]
    const float* vbuf   = (const float*)d_in[3];   // [8,8,8192,128]
    const float* Wq     = (const float*)d_in[4];   // [4096,4096]
    const float* Wo     = (const float*)d_in[5];   // [4096,4096]

    float* out   = (float*)d_out;                  // [8,4096]
    float* probs = out + NB * DIM;                 // [8,32,1,128]

    char* ws = (char*)d_ws;
    unsigned* impbits = (unsigned*)ws;              // 8*8192*4 = 262144 B
    int*   topkb = (int*)(ws + 262144);             // 8*128*4  =   4096 B
    float* q     = (float*)(ws + 266240);           // 8*4096*4 = 131072 B
    float* ctx   = (float*)(ws + 397312);           // 8*4096*4 = 131072 B

    void* args[] = {
        (void*)&hidden, (void*)&attn_w, (void*)&kbuf, (void*)&vbuf,
        (void*)&Wq, (void*)&Wo, (void*)&out, (void*)&probs,
        (void*)&impbits, (void*)&topkb, (void*)&q, (void*)&ctx,
    };
    hipLaunchCooperativeKernel((void*)mega_kernel, dim3(256), dim3(512), args, 0, stream);
}

// Round 5
// 238.801 us; speedup vs baseline: 1.1431x; 1.1431x over previous
//
#include <hip/hip_runtime.h>

#define S_TOK 8192
#define NB 8
#define HQ 32
#define HKV 8
#define DH 128
#define KK 128
#define DIM 4096
#define NCOL4 (DIM / 4)   // 1024
#define NBLK 256          // grid size; all blocks co-resident (1 per CU)

// ---------------- custom grid barrier (device-scope, replay-safe) ----------------
// ctr starts at 0 each launch (hipMemsetAsync). Each barrier adds exactly NBLK, so
// the generation base is always a multiple of NBLK; the arriving block's target is
// (old & ~(NBLK-1)) + NBLK. Only thread 0 spins; whole block waits at syncthreads.
__device__ __forceinline__ void gridbar(unsigned* __restrict__ ctr, int t) {
    __syncthreads();
    if (t == 0) {
        __threadfence();   // release: make this block's prior writes device-visible
        unsigned o = __hip_atomic_fetch_add(ctr, 1u, __ATOMIC_ACQ_REL,
                                            __HIP_MEMORY_SCOPE_AGENT);
        unsigned target = (o & ~(unsigned)(NBLK - 1)) + NBLK;
        while (__hip_atomic_load(ctr, __ATOMIC_ACQUIRE,
                                 __HIP_MEMORY_SCOPE_AGENT) < target) {
            __builtin_amdgcn_s_sleep(2);
        }
    }
    __syncthreads();
    __threadfence();       // acquire: invalidate L1 so post-barrier reads see fresh data
}

// ---------------- GEMV: 2 rows per wave, x register-shared across rows ----------------
__device__ __forceinline__ void gemv_rows(const float* __restrict__ W,
                                          const float* __restrict__ x,
                                          float* __restrict__ y,
                                          int rstart, int rcnt, int t) {
    const int wv = t >> 6, lane = t & 63;
    const float4* W4 = (const float4*)W;
    const float4* x4 = (const float4*)x;
    for (int p = wv; 2 * p < rcnt; p += 8) {
        const int r0 = rstart + 2 * p;
        const bool has1 = (2 * p + 1) < rcnt;
        const int r1 = has1 ? (r0 + 1) : r0;
        float acc0[NB], acc1[NB];
#pragma unroll
        for (int b = 0; b < NB; ++b) { acc0[b] = 0.f; acc1[b] = 0.f; }
#pragma unroll 2
        for (int it = 0; it < 16; ++it) {
            const int c = lane + it * 64;
            float4 w0 = W4[(size_t)r0 * NCOL4 + c];
            float4 w1 = W4[(size_t)r1 * NCOL4 + c];
#pragma unroll
            for (int b = 0; b < NB; ++b) {
                float4 xv = x4[(size_t)b * NCOL4 + c];
                acc0[b] += w0.x * xv.x + w0.y * xv.y + w0.z * xv.z + w0.w * xv.w;
                acc1[b] += w1.x * xv.x + w1.y * xv.y + w1.z * xv.z + w1.w * xv.w;
            }
        }
#pragma unroll
        for (int b = 0; b < NB; ++b) {
#pragma unroll
            for (int o = 32; o > 0; o >>= 1) {
                acc0[b] += __shfl_down(acc0[b], o);
                acc1[b] += __shfl_down(acc1[b], o);
            }
        }
        if (lane == 0) {
#pragma unroll
            for (int b = 0; b < NB; ++b) {
                y[(size_t)b * DIM + r0] = acc0[b];
                if (has1) y[(size_t)b * DIM + r1] = acc1[b];
            }
        }
    }
}

__global__ __launch_bounds__(512, 1) void mega_kernel(
    const float* __restrict__ hidden, const float* __restrict__ attn_w,
    const float* __restrict__ kbuf, const float* __restrict__ vbuf,
    const float* __restrict__ Wq, const float* __restrict__ Wo,
    float* __restrict__ out, float* __restrict__ probs,
    unsigned* __restrict__ impbits, int* __restrict__ topkbuf,
    float* __restrict__ q, float* __restrict__ ctx,
    unsigned* __restrict__ barctr) {

    __shared__ __align__(16) unsigned mb[S_TOK];   // 32 KB (topk)
    __shared__ __align__(16) int hist[256];
    __shared__ unsigned sprefix;
    __shared__ int skrem;
    __shared__ int nsel;
    __shared__ unsigned selb[KK];
    __shared__ int seli[KK];
    __shared__ float qs[DH];
    __shared__ float scs[KK];
    __shared__ float ps[KK];
    __shared__ int idxs[KK];
    __shared__ float red2[2];
    __shared__ float red3[2];
    __shared__ float part[3][DH];

    const int t = threadIdx.x;
    const int bl = blockIdx.x;

    // ========== Phase A: importance, serial h=0..31 scalar sum (bit-exact vs R1/R3) ===
    // 65536 tokens; 256 tokens per block, one lane each (4 waves active).
    if (t < 256) {
        const int tok = bl * 256 + t;
        const int b = tok >> 13;             // /8192
        const int s = tok & (S_TOK - 1);
        const float* p = attn_w + (size_t)b * HQ * S_TOK + s;
        float acc = 0.f;
#pragma unroll
        for (int h = 0; h < HQ; ++h) acc += p[(size_t)h * S_TOK];
        unsigned uu = __float_as_uint(acc * (1.0f / 32.0f));
        uu = (uu & 0x80000000u) ? ~uu : (uu | 0x80000000u);   // monotone map
        impbits[tok] = uu;
    }
    gridbar(barctr, t);

    // ========== Phase B: topk (blocks 0..7) + Wq GEMV (all blocks) ====================
    if (bl < NB) {
        const int b = bl;
        const unsigned* ip = impbits + (size_t)b * S_TOK;
        for (int i = t; i < S_TOK; i += 512) mb[i] = ip[i];
        if (t == 0) { sprefix = 0u; skrem = KK; nsel = 0; }
        __syncthreads();

        // radix-256 select: bit pattern T of the 128th largest
        for (int shift = 24; shift >= 0; shift -= 8) {
            if (t < 256) hist[t] = 0;
            __syncthreads();
            const unsigned pfx = sprefix;
            const int krem = skrem;
            if (shift == 24) {
                // values cluster into few exponent bins -> ballot-aggregate
                for (int i = t; i < S_TOK; i += 512) {
                    int bin = mb[i] >> 24;
                    unsigned long long rem = __ballot(1);
                    while (rem) {
                        int fl = (int)__builtin_ctzll(rem);
                        int fbin = __shfl(bin, fl);
                        unsigned long long match = __ballot(bin == fbin);
                        if ((t & 63) == fl) atomicAdd(&hist[fbin], (int)__popcll(match));
                        rem &= ~match;
                    }
                }
            } else {
                const unsigned pmask = 0xFFFFFFFFu << (shift + 8);
                for (int i = t; i < S_TOK; i += 512) {
                    unsigned u = mb[i];
                    if ((u & pmask) == pfx) atomicAdd(&hist[(u >> shift) & 255], 1);
                }
            }
            __syncthreads();
            // wave 0: parallel descending-bin scan
            if (t < 64) {
                int4 h4 = *(const int4*)&hist[252 - 4 * t];
                int h0 = h4.w, h1 = h4.z, h2 = h4.y, h3 = h4.x;   // descending-bin order
                int c0 = h0, c1 = c0 + h1, c2 = c1 + h2, c3 = c2 + h3;
                int inc = c3;
#pragma unroll
                for (int o = 1; o < 64; o <<= 1) {
                    int yv = __shfl_up(inc, o);
                    if (t >= o) inc += yv;
                }
                int excl = inc - c3;
                int cand = -1, before = 0;
                if      (excl + c0 >= krem) { cand = 0; before = excl; }
                else if (excl + c1 >= krem) { cand = 1; before = excl + c0; }
                else if (excl + c2 >= krem) { cand = 2; before = excl + c1; }
                else if (excl + c3 >= krem) { cand = 3; before = excl + c2; }
                unsigned long long ball = __ballot(cand >= 0);
                int win = (int)__builtin_ctzll(ball);
                if (t == win) {
                    int p = 4 * t + cand;
                    sprefix = pfx | ((unsigned)(255 - p) << shift);
                    skrem = krem - before;
                }
            }
            __syncthreads();
        }
        const unsigned T = sprefix;

        // collect strictly-greater (unordered; sorted below)
        for (int i = t; i < S_TOK; i += 512) {
            unsigned u = mb[i];
            if (u > T) {
                int p = atomicAdd(&nsel, 1);
                selb[p] = u; seli[p] = i;
            }
        }
        __syncthreads();
        const int g = nsel;
        const int r = KK - g;          // >= 1 by construction

        // wave 0: ordered scan collects the r smallest-index ties
        if (t < 64) {
            int found = 0;
            for (int base0 = 0; base0 < S_TOK && found < r; base0 += 64) {
                bool is_tie = (mb[base0 + t] == T);
                unsigned long long ball = __ballot(is_tie);
                int pos = (int)__popcll(ball & ((1ull << t) - 1ull));
                if (is_tie && found + pos < r) {
                    selb[g + found + pos] = T;
                    seli[g + found + pos] = base0 + t;
                }
                found += (int)__popcll(ball);
            }
        }
        __syncthreads();

        // bitonic sort 128: value descending, index ascending
        for (int ksz = 2; ksz <= KK; ksz <<= 1) {
            for (int j = ksz >> 1; j > 0; j >>= 1) {
                if (t < KK) {
                    int i = t, l = i ^ j;
                    if (l > i) {
                        bool up = ((i & ksz) == 0);
                        unsigned ab = selb[i], cb = selb[l];
                        int ai = seli[i], ci = seli[l];
                        bool aFirst = (ab > cb) || (ab == cb && ai < ci);
                        if (up ? !aFirst : aFirst) {
                            selb[i] = cb; selb[l] = ab;
                            seli[i] = ci; seli[l] = ai;
                        }
                    }
                }
                __syncthreads();
            }
        }
        if (t < KK) topkbuf[b * KK + t] = seli[t];
    }

    // Wq GEMV: blocks 0-7 get 6 rows (after topk); of the rest, first 80 get 17,
    // remaining 168 get 16  (48 + 80*17 + 168*16 = 4096).
    {
        int rstart, rcnt;
        if (bl < NB) { rstart = bl * 6; rcnt = 6; }
        else {
            int idx = bl - NB;
            int extra = (idx < 80) ? idx : 80;
            rstart = 48 + idx * 16 + extra;
            rcnt = 16 + ((idx < 80) ? 1 : 0);
        }
        gemv_rows(Wq, hidden, q, rstart, rcnt, t);
    }
    gridbar(barctr, t);

    // ========== Phase C: pruned attention, one block per (b,h) =======================
    {
        const int b = bl >> 5, h = bl & 31, kvh = h >> 2;

        if (t < DH) qs[t] = q[(size_t)(b * HQ + h) * DH + t] * 0.088388347648318447f;
        if (t < KK) idxs[t] = topkbuf[b * KK + t];
        __syncthreads();

        // scores: 4 threads per token, 32-dim quarter dots
        {
            const int tok = t >> 2, qpart = t & 3;
            const float4* k4 = (const float4*)(kbuf +
                ((size_t)(b * HKV + kvh) * S_TOK + idxs[tok]) * DH + qpart * 32);
            float sc = 0.f;
#pragma unroll
            for (int d4 = 0; d4 < 8; ++d4) {
                float4 kv = k4[d4];
                int d0 = qpart * 32 + d4 * 4;
                sc += qs[d0] * kv.x + qs[d0 + 1] * kv.y + qs[d0 + 2] * kv.z + qs[d0 + 3] * kv.w;
            }
            sc += __shfl_xor(sc, 1);
            sc += __shfl_xor(sc, 2);
            if (qpart == 0) scs[tok] = sc;
        }
        __syncthreads();

        // softmax over 128 tokens (threads 0..127 hold one token each)
        float sc = (t < KK) ? scs[t] : -3.4e38f;
        if (t < KK) {
            float m = sc;
            for (int o = 32; o > 0; o >>= 1) m = fmaxf(m, __shfl_down(m, o));
            if ((t & 63) == 0) red2[t >> 6] = m;
        }
        __syncthreads();
        const float mx = fmaxf(red2[0], red2[1]);
        float p = 0.f;
        if (t < KK) {
            p = expf(sc - mx);
            float sm = p;
            for (int o = 32; o > 0; o >>= 1) sm += __shfl_down(sm, o);
            if ((t & 63) == 0) red3[t >> 6] = sm;
        }
        __syncthreads();
        if (t < KK) {
            p /= (red3[0] + red3[1]);
            ps[t] = p;
            probs[(size_t)(b * HQ + h) * KK + t] = p;
        }
        __syncthreads();

        // PV: 4 groups x 128 dims, 32 tokens per group, LDS combine
        {
            const int d = t & (DH - 1), grp = t >> 7;
            const float* vbase = vbuf + (size_t)(b * HKV + kvh) * S_TOK * DH;
            float acc = 0.f;
            const int s0 = grp * 32;
#pragma unroll 4
            for (int s2 = s0; s2 < s0 + 32; ++s2) {
                acc += ps[s2] * vbase[(size_t)idxs[s2] * DH + d];
            }
            if (grp) part[grp - 1][d] = acc;
            __syncthreads();
            if (grp == 0)
                ctx[(size_t)(b * HQ + h) * DH + d] = acc + part[0][d] + part[1][d] + part[2][d];
        }
    }
    gridbar(barctr, t);

    // ========== Phase D: Wo GEMV, exactly 16 rows per block ==========================
    gemv_rows(Wo, ctx, out, bl * 16, 16, t);
}

// ---------------- launcher ----------------
extern "C" void kernel_launch(void* const* d_in, const int* in_sizes, int n_in,
                              void* d_out, int out_size, void* d_ws, size_t ws_size,
                              hipStream_t stream) {
    const float* hidden = (const float*)d_in[0];   // [8,1,4096]
    const float* attn_w = (const float*)d_in[1];   // [8,32,1,8192]
    const float* kbuf   = (const float*)d_in[2];   // [8,8,8192,128]
    const float* vbuf   = (const float*)d_in[3];   // [8,8,8192,128]
    const float* Wq     = (const float*)d_in[4];   // [4096,4096]
    const float* Wo     = (const float*)d_in[5];   // [4096,4096]

    float* out   = (float*)d_out;                  // [8,4096]
    float* probs = out + NB * DIM;                 // [8,32,1,128]

    char* ws = (char*)d_ws;
    unsigned* impbits = (unsigned*)ws;              // 8*8192*4 = 262144 B
    int*   topkb = (int*)(ws + 262144);             // 8*128*4  =   4096 B
    float* q     = (float*)(ws + 266240);           // 8*4096*4 = 131072 B
    float* ctx   = (float*)(ws + 397312);           // 8*4096*4 = 131072 B
    unsigned* barctr = (unsigned*)(ws + 528384);    // 128 B barrier counter

    // barrier counter must start at 0 each launch (workspace is poisoned between runs)
    hipMemsetAsync(barctr, 0, 128, stream);

    mega_kernel<<<NBLK, 512, 0, stream>>>(hidden, attn_w, kbuf, vbuf, Wq, Wo,
                                          out, probs, impbits, topkb, q, ctx, barctr);
}

// Round 6
// 102.825 us; speedup vs baseline: 2.6546x; 2.3224x over previous
//
#include <hip/hip_runtime.h>

#define S_TOK 8192
#define NB 8
#define HQ 32
#define HKV 8
#define DH 128
#define KK 128
#define DIM 4096
#define NCOL4 (DIM / 4)   // 1024

// ---------------- GEMV core: 2 rows per block, 256 threads ----------------
// Column order per thread (c = t, t+256, t+512, t+768) and reduction order
// (shfl over 64 lanes, then 4-wave LDS combine) are BIT-IDENTICAL to the
// verified R1 gemv_b8 -> outputs bit-exact vs R1.
__device__ __forceinline__ void gemv2(const float* __restrict__ W,
                                      const float* __restrict__ x,
                                      float* __restrict__ y,
                                      int r0, int t, float* red /* [4][16] */) {
    const int r1 = r0 + 1;
    const float4* w0p = (const float4*)(W + (size_t)r0 * DIM);
    const float4* w1p = (const float4*)(W + (size_t)r1 * DIM);
    const float4* x4 = (const float4*)x;
    float acc0[NB], acc1[NB];
#pragma unroll
    for (int b = 0; b < NB; ++b) { acc0[b] = 0.f; acc1[b] = 0.f; }
#pragma unroll 2
    for (int it = 0; it < 4; ++it) {
        const int c = t + it * 256;
        float4 w0 = w0p[c];
        float4 w1 = w1p[c];
#pragma unroll
        for (int b = 0; b < NB; ++b) {
            float4 xv = x4[(size_t)b * NCOL4 + c];
            acc0[b] += w0.x * xv.x + w0.y * xv.y + w0.z * xv.z + w0.w * xv.w;
            acc1[b] += w1.x * xv.x + w1.y * xv.y + w1.z * xv.z + w1.w * xv.w;
        }
    }
    const int lane = t & 63, wv = t >> 6;
#pragma unroll
    for (int b = 0; b < NB; ++b) {
#pragma unroll
        for (int o = 32; o > 0; o >>= 1) {
            acc0[b] += __shfl_down(acc0[b], o);
            acc1[b] += __shfl_down(acc1[b], o);
        }
    }
    if (lane == 0) {
#pragma unroll
        for (int b = 0; b < NB; ++b) {
            red[wv * 16 + b] = acc0[b];
            red[wv * 16 + 8 + b] = acc1[b];
        }
    }
    __syncthreads();
    if (t < 16) {
        float s = red[0 * 16 + t] + red[1 * 16 + t] + red[2 * 16 + t] + red[3 * 16 + t];
        int b = t & 7;
        int row = (t >> 3) ? r1 : r0;
        y[(size_t)b * DIM + row] = s;
    }
}

// ---------------- Kernel 1: fused { topk (blk 0..7) | importance (blk 8..263) |
//                                    Wq GEMV 2-row (blk 264..2311) } ----------------
// topk blocks spin on an arrival counter until all 256 importance blocks signal.
// Deadlock-free: waiters (8) << CUs, producers never wait.
__global__ __launch_bounds__(256) void fused_kernel(const float* __restrict__ attn_w,
                                                    const float* __restrict__ Wq,
                                                    const float* __restrict__ hidden,
                                                    unsigned* __restrict__ impbits,
                                                    int* __restrict__ topk,
                                                    float* __restrict__ q,
                                                    unsigned* __restrict__ impdone) {
    __shared__ __align__(16) unsigned mb[S_TOK];   // 32 KB (topk path)
    __shared__ __align__(16) int hist[256];
    __shared__ unsigned sprefix;
    __shared__ int skrem;
    __shared__ int nsel;
    __shared__ unsigned selb[KK];
    __shared__ int seli[KK];
    __shared__ float redg[4 * 16];                 // (gemv path)

    const int t = threadIdx.x;
    const int bl = blockIdx.x;

    if (bl >= NB + 256) {
        // ---------- Wq GEMV path ----------
        gemv2(Wq, hidden, q, (bl - NB - 256) * 2, t, redg);
        return;
    }

    if (bl >= NB) {
        // ---------- importance path: serial h=0..31 sum (bit-exact vs R1) ----------
        const int tok = (bl - NB) * 256 + t;       // covers NB*S_TOK = 65536
        const int b = tok >> 13;                   // /8192
        const int s = tok & (S_TOK - 1);
        const float* p = attn_w + (size_t)b * HQ * S_TOK + s;
        float acc = 0.f;
#pragma unroll
        for (int h = 0; h < HQ; ++h) acc += p[(size_t)h * S_TOK];
        unsigned uu = __float_as_uint(acc * (1.0f / 32.0f));
        uu = (uu & 0x80000000u) ? ~uu : (uu | 0x80000000u);   // monotone map
        impbits[tok] = uu;
        __threadfence();
        __syncthreads();
        if (t == 0)
            __hip_atomic_fetch_add(impdone, 1u, __ATOMIC_ACQ_REL, __HIP_MEMORY_SCOPE_AGENT);
        return;
    }

    // ---------- topk path: wait for all importance blocks ----------
    if (t == 0) {
        while (__hip_atomic_load(impdone, __ATOMIC_ACQUIRE, __HIP_MEMORY_SCOPE_AGENT) < 256u)
            __builtin_amdgcn_s_sleep(2);
    }
    __syncthreads();
    __threadfence();

    const int b = bl;
    const unsigned* ip = impbits + (size_t)b * S_TOK;
    for (int i = t; i < S_TOK; i += 256) mb[i] = ip[i];
    if (t == 0) { sprefix = 0u; skrem = KK; nsel = 0; }
    __syncthreads();

    // radix-256 select: bit pattern T of the 128th largest
    for (int shift = 24; shift >= 0; shift -= 8) {
        hist[t] = 0;
        __syncthreads();
        const unsigned pfx = sprefix;
        const int krem = skrem;
        if (shift == 24) {
            // values cluster into few exponent bins -> ballot-aggregate
            for (int i = t; i < S_TOK; i += 256) {
                int bin = mb[i] >> 24;
                unsigned long long rem = __ballot(1);
                while (rem) {
                    int fl = (int)__builtin_ctzll(rem);
                    int fbin = __shfl(bin, fl);
                    unsigned long long match = __ballot(bin == fbin);
                    if ((t & 63) == fl) atomicAdd(&hist[fbin], (int)__popcll(match));
                    rem &= ~match;
                }
            }
        } else {
            const unsigned pmask = 0xFFFFFFFFu << (shift + 8);
            for (int i = t; i < S_TOK; i += 256) {
                unsigned u = mb[i];
                if ((u & pmask) == pfx) atomicAdd(&hist[(u >> shift) & 255], 1);
            }
        }
        __syncthreads();
        // wave 0: parallel descending-bin scan
        if (t < 64) {
            int4 h4 = *(const int4*)&hist[252 - 4 * t];
            int h0 = h4.w, h1 = h4.z, h2 = h4.y, h3 = h4.x;   // descending-bin order
            int c0 = h0, c1 = c0 + h1, c2 = c1 + h2, c3 = c2 + h3;
            int inc = c3;
#pragma unroll
            for (int o = 1; o < 64; o <<= 1) {
                int yv = __shfl_up(inc, o);
                if (t >= o) inc += yv;
            }
            int excl = inc - c3;
            int cand = -1, before = 0;
            if      (excl + c0 >= krem) { cand = 0; before = excl; }
            else if (excl + c1 >= krem) { cand = 1; before = excl + c0; }
            else if (excl + c2 >= krem) { cand = 2; before = excl + c1; }
            else if (excl + c3 >= krem) { cand = 3; before = excl + c2; }
            unsigned long long ball = __ballot(cand >= 0);
            int win = (int)__builtin_ctzll(ball);
            if (t == win) {
                int p = 4 * t + cand;
                sprefix = pfx | ((unsigned)(255 - p) << shift);
                skrem = krem - before;
            }
        }
        __syncthreads();
    }
    const unsigned T = sprefix;

    // collect strictly-greater (unordered; sorted below)
    for (int i = t; i < S_TOK; i += 256) {
        unsigned u = mb[i];
        if (u > T) {
            int p = atomicAdd(&nsel, 1);
            selb[p] = u; seli[p] = i;
        }
    }
    __syncthreads();
    const int g = nsel;
    const int r = KK - g;          // >= 1 by construction

    // wave 0: ordered scan collects the r smallest-index ties
    if (t < 64) {
        int found = 0;
        for (int base0 = 0; base0 < S_TOK && found < r; base0 += 64) {
            bool is_tie = (mb[base0 + t] == T);
            unsigned long long ball = __ballot(is_tie);
            int pos = (int)__popcll(ball & ((1ull << t) - 1ull));
            if (is_tie && found + pos < r) {
                selb[g + found + pos] = T;
                seli[g + found + pos] = base0 + t;
            }
            found += (int)__popcll(ball);
        }
    }
    __syncthreads();

    // bitonic sort 128: value descending, index ascending
    for (int ksz = 2; ksz <= KK; ksz <<= 1) {
        for (int j = ksz >> 1; j > 0; j >>= 1) {
            if (t < KK) {
                int i = t, l = i ^ j;
                if (l > i) {
                    bool up = ((i & ksz) == 0);
                    unsigned ab = selb[i], cb = selb[l];
                    int ai = seli[i], ci = seli[l];
                    bool aFirst = (ab > cb) || (ab == cb && ai < ci);
                    if (up ? !aFirst : aFirst) {
                        selb[i] = cb; selb[l] = ab;
                        seli[i] = ci; seli[l] = ai;
                    }
                }
            }
            __syncthreads();
        }
    }
    if (t < KK) topk[b * KK + t] = seli[t];
}

// ---------------- Kernel 2: pruned attention, 512 threads per (b,h) ----------------
__global__ __launch_bounds__(512) void attn_kernel(const float* __restrict__ q,
                                                   const float* __restrict__ k,
                                                   const float* __restrict__ v,
                                                   const int* __restrict__ topk,
                                                   float* __restrict__ ctx,
                                                   float* __restrict__ probs_out) {
    const int bh = blockIdx.x;
    const int b = bh >> 5, h = bh & 31, kvh = h >> 2;
    const int t = threadIdx.x;   // 512 threads

    __shared__ float qs[DH];
    __shared__ float scs[KK];
    __shared__ float ps[KK];
    __shared__ int idxs[KK];
    __shared__ float red2[2];
    __shared__ float red3[2];
    __shared__ float part[3][DH];

    if (t < DH) qs[t] = q[(size_t)(b * HQ + h) * DH + t] * 0.088388347648318447f; // 1/sqrt(128)
    if (t < KK) idxs[t] = topk[b * KK + t];
    __syncthreads();

    // scores: 4 threads per token, 32-dim quarter dots
    {
        const int tok = t >> 2, qpart = t & 3;
        const float4* k4 = (const float4*)(k +
            ((size_t)(b * HKV + kvh) * S_TOK + idxs[tok]) * DH + qpart * 32);
        float sc = 0.f;
#pragma unroll
        for (int d4 = 0; d4 < 8; ++d4) {
            float4 kv = k4[d4];
            int d0 = qpart * 32 + d4 * 4;
            sc += qs[d0] * kv.x + qs[d0 + 1] * kv.y + qs[d0 + 2] * kv.z + qs[d0 + 3] * kv.w;
        }
        sc += __shfl_xor(sc, 1);
        sc += __shfl_xor(sc, 2);
        if (qpart == 0) scs[tok] = sc;
    }
    __syncthreads();

    // softmax over 128 tokens (threads 0..127 hold one token each)
    float sc = (t < KK) ? scs[t] : -3.4e38f;
    if (t < KK) {
        float m = sc;
        for (int o = 32; o > 0; o >>= 1) m = fmaxf(m, __shfl_down(m, o));
        if ((t & 63) == 0) red2[t >> 6] = m;
    }
    __syncthreads();
    const float mx = fmaxf(red2[0], red2[1]);
    float p = 0.f;
    if (t < KK) {
        p = expf(sc - mx);
        float sm = p;
        for (int o = 32; o > 0; o >>= 1) sm += __shfl_down(sm, o);
        if ((t & 63) == 0) red3[t >> 6] = sm;
    }
    __syncthreads();
    if (t < KK) {
        p /= (red3[0] + red3[1]);
        ps[t] = p;
        probs_out[(size_t)(b * HQ + h) * KK + t] = p;
    }
    __syncthreads();

    // PV: 4 groups x 128 dims, 32 tokens per group, LDS combine
    {
        const int d = t & (DH - 1), grp = t >> 7;
        const float* vbase = v + (size_t)(b * HKV + kvh) * S_TOK * DH;
        float acc = 0.f;
        const int s0 = grp * 32;
#pragma unroll 4
        for (int s2 = s0; s2 < s0 + 32; ++s2) {
            acc += ps[s2] * vbase[(size_t)idxs[s2] * DH + d];
        }
        if (grp) part[grp - 1][d] = acc;
        __syncthreads();
        if (grp == 0)
            ctx[(size_t)(b * HQ + h) * DH + d] = acc + part[0][d] + part[1][d] + part[2][d];
    }
}

// ---------------- Kernel 3: Wo GEMV, 2 rows per block ----------------
__global__ __launch_bounds__(256) void gemv_wo_kernel(const float* __restrict__ Wo,
                                                      const float* __restrict__ ctx,
                                                      float* __restrict__ out) {
    __shared__ float redg[4 * 16];
    gemv2(Wo, ctx, out, blockIdx.x * 2, threadIdx.x, redg);
}

// ---------------- launcher ----------------
extern "C" void kernel_launch(void* const* d_in, const int* in_sizes, int n_in,
                              void* d_out, int out_size, void* d_ws, size_t ws_size,
                              hipStream_t stream) {
    const float* hidden = (const float*)d_in[0];   // [8,1,4096]
    const float* attn_w = (const float*)d_in[1];   // [8,32,1,8192]
    const float* k      = (const float*)d_in[2];   // [8,8,8192,128]
    const float* v      = (const float*)d_in[3];   // [8,8,8192,128]
    const float* Wq     = (const float*)d_in[4];   // [4096,4096]
    const float* Wo     = (const float*)d_in[5];   // [4096,4096]

    float* out   = (float*)d_out;                  // [8,4096]
    float* probs = out + NB * DIM;                 // [8,32,1,128]

    char* ws = (char*)d_ws;
    unsigned* impbits = (unsigned*)ws;              // 8*8192*4 = 262144 B
    int*   topkb = (int*)(ws + 262144);             // 8*128*4  =   4096 B
    float* q     = (float*)(ws + 266240);           // 8*4096*4 = 131072 B
    float* ctx   = (float*)(ws + 397312);           // 8*4096*4 = 131072 B
    unsigned* impdone = (unsigned*)(ws + 528384);   // arrival counter

    hipMemsetAsync(impdone, 0, 64, stream);         // counter starts at 0 each launch

    // blocks 0..7: topk (spin-wait); 8..263: importance; 264..2311: Wq GEMV (2 rows)
    fused_kernel<<<NB + 256 + DIM / 2, 256, 0, stream>>>(attn_w, Wq, hidden,
                                                         impbits, topkb, q, impdone);
    attn_kernel<<<NB * HQ, 512, 0, stream>>>(q, k, v, topkb, ctx, probs);
    gemv_wo_kernel<<<DIM / 2, 256, 0, stream>>>(Wo, ctx, out);
}